// Round 1
// baseline (2954.602 us; speedup 1.0000x reference)
//
#include <hip/hip_runtime.h>
#include <math.h>

// ---------------------------------------------------------------------------
// NoPropDTEncoder forward, restructured:
//  - pooling + 4 attention stages as 1-pass online-softmax streams over x_feat
//    (scores via Qk = W_k_h^T q; weighted sums over raw x; o = W_v xw + bv)
//  - FFT branch: only modes 0..15 matter; ifft+proj folded into C/S matrices
//  - small fp32 tiled GEMMs for q / Qk / o / z_attn
// ws usage ~17 MB (float offsets documented below).
// ---------------------------------------------------------------------------

#define DEV __device__ __forceinline__

constexpr int Bv  = 256;
constexpr int Sv  = 512;
constexpr int Dv  = 768;
constexpr int Hv  = 8;
constexpr int DHv = 96;
constexpr int NCv = 14;

DEV float4 ld4(const float* p) { return *reinterpret_cast<const float4*>(p); }

// ---------------------------------------------------------------------------
// Flash pass: one block per b (512 threads = 8 waves). Each wave handles 64
// rows of x[b], pair-at-a-time, online softmax with NH running accumulators.
// Lane owns columns {4*lane + 256*j : j=0..2}.
// ---------------------------------------------------------------------------
template<int NH>
__global__ __launch_bounds__(512, 2)
void flash_kernel(const float* __restrict__ x,    // (B,S,D)
                  const float* __restrict__ qk,   // NH==1: (D) shared; else (B,NH,D)
                  float* __restrict__ outp,       // (B,NH,D): normalized weighted sum
                  float scale)
{
    __shared__ float qks[NH * Dv];
    __shared__ float buf[4][NH * Dv];
    __shared__ float mlb[8][NH][2];

    const int b    = blockIdx.x;
    const int tid  = threadIdx.x;
    const int wave = tid >> 6;
    const int lane = tid & 63;

    // stage query vectors to LDS
    const float* qsrc = (NH == 1) ? qk : (qk + (size_t)b * NH * Dv);
    for (int v4 = tid; v4 < NH * (Dv / 4); v4 += 512) {
        *reinterpret_cast<float4*>(&qks[v4 * 4]) = ld4(qsrc + v4 * 4);
    }
    __syncthreads();

    float4 acc[NH][3];
    float m[NH], l[NH];
#pragma unroll
    for (int h = 0; h < NH; ++h) {
        m[h] = -INFINITY; l[h] = 0.f;
#pragma unroll
        for (int j = 0; j < 3; ++j) acc[h][j] = make_float4(0.f, 0.f, 0.f, 0.f);
    }

    const int s0 = wave * 64;
    const float* base = x + ((size_t)b * Sv + s0) * Dv + 4 * lane;

    float4 c0[3], c1[3];
#pragma unroll
    for (int j = 0; j < 3; ++j) { c0[j] = ld4(base + 256 * j); c1[j] = ld4(base + Dv + 256 * j); }

    for (int it = 0; it < 32; ++it) {
        float4 nx0[3], nx1[3];
        if (it < 31) {
            const float* nb = base + (size_t)(2 * it + 2) * Dv;
#pragma unroll
            for (int j = 0; j < 3; ++j) { nx0[j] = ld4(nb + 256 * j); nx1[j] = ld4(nb + Dv + 256 * j); }
        }
        float p0[NH], p1[NH];
#pragma unroll
        for (int h = 0; h < NH; ++h) {
            float a0 = 0.f, a1 = 0.f;
#pragma unroll
            for (int j = 0; j < 3; ++j) {
                const float4 q4 = *reinterpret_cast<const float4*>(&qks[h * Dv + 4 * lane + 256 * j]);
                a0 = fmaf(q4.x, c0[j].x, a0); a0 = fmaf(q4.y, c0[j].y, a0);
                a0 = fmaf(q4.z, c0[j].z, a0); a0 = fmaf(q4.w, c0[j].w, a0);
                a1 = fmaf(q4.x, c1[j].x, a1); a1 = fmaf(q4.y, c1[j].y, a1);
                a1 = fmaf(q4.z, c1[j].z, a1); a1 = fmaf(q4.w, c1[j].w, a1);
            }
            p0[h] = a0; p1[h] = a1;
        }
        // butterfly reduce across 64 lanes (result identical in all lanes)
#pragma unroll
        for (int dd = 1; dd < 64; dd <<= 1) {
#pragma unroll
            for (int h = 0; h < NH; ++h) {
                p0[h] += __shfl_xor(p0[h], dd);
                p1[h] += __shfl_xor(p1[h], dd);
            }
        }
#pragma unroll
        for (int h = 0; h < NH; ++h) {
            float sc0 = p0[h] * scale, sc1 = p1[h] * scale;
            float mx = fmaxf(sc0, sc1);
            if (mx > m[h]) {               // wave-uniform branch
                float r = expf(m[h] - mx); // first iter: expf(-inf)=0
                l[h] *= r;
#pragma unroll
                for (int j = 0; j < 3; ++j) {
                    acc[h][j].x *= r; acc[h][j].y *= r; acc[h][j].z *= r; acc[h][j].w *= r;
                }
                m[h] = mx;
            }
            float w0 = expf(sc0 - m[h]);
            float w1 = expf(sc1 - m[h]);
            l[h] += w0 + w1;
#pragma unroll
            for (int j = 0; j < 3; ++j) {
                acc[h][j].x = fmaf(w1, c1[j].x, fmaf(w0, c0[j].x, acc[h][j].x));
                acc[h][j].y = fmaf(w1, c1[j].y, fmaf(w0, c0[j].y, acc[h][j].y));
                acc[h][j].z = fmaf(w1, c1[j].z, fmaf(w0, c0[j].z, acc[h][j].z));
                acc[h][j].w = fmaf(w1, c1[j].w, fmaf(w0, c0[j].w, acc[h][j].w));
            }
        }
        if (it < 31) {
#pragma unroll
            for (int j = 0; j < 3; ++j) { c0[j] = nx0[j]; c1[j] = nx1[j]; }
        }
    }

    // ---- merge 8 waves ----
    if (lane == 0) {
#pragma unroll
        for (int h = 0; h < NH; ++h) { mlb[wave][h][0] = m[h]; mlb[wave][h][1] = l[h]; }
    }
    __syncthreads();
    float L[NH];
#pragma unroll
    for (int h = 0; h < NH; ++h) {
        float g_ = mlb[0][h][0];
#pragma unroll
        for (int w = 1; w < 8; ++w) g_ = fmaxf(g_, mlb[w][h][0]);
        float Ls = 0.f;
#pragma unroll
        for (int w = 0; w < 8; ++w) Ls += mlb[w][h][1] * expf(mlb[w][h][0] - g_);
        L[h] = Ls;
        float f = expf(m[h] - g_);
#pragma unroll
        for (int j = 0; j < 3; ++j) {
            acc[h][j].x *= f; acc[h][j].y *= f; acc[h][j].z *= f; acc[h][j].w *= f;
        }
    }
    const int cb = 4 * lane;
    if (wave >= 4) {
#pragma unroll
        for (int h = 0; h < NH; ++h)
#pragma unroll
            for (int j = 0; j < 3; ++j)
                *reinterpret_cast<float4*>(&buf[wave - 4][h * Dv + cb + 256 * j]) = acc[h][j];
    }
    __syncthreads();
    if (wave < 4) {
#pragma unroll
        for (int h = 0; h < NH; ++h)
#pragma unroll
            for (int j = 0; j < 3; ++j) {
                float4 v = *reinterpret_cast<const float4*>(&buf[wave][h * Dv + cb + 256 * j]);
                acc[h][j].x += v.x; acc[h][j].y += v.y; acc[h][j].z += v.z; acc[h][j].w += v.w;
            }
    }
    __syncthreads();
    if (wave == 2 || wave == 3) {
#pragma unroll
        for (int h = 0; h < NH; ++h)
#pragma unroll
            for (int j = 0; j < 3; ++j)
                *reinterpret_cast<float4*>(&buf[wave - 2][h * Dv + cb + 256 * j]) = acc[h][j];
    }
    __syncthreads();
    if (wave < 2) {
#pragma unroll
        for (int h = 0; h < NH; ++h)
#pragma unroll
            for (int j = 0; j < 3; ++j) {
                float4 v = *reinterpret_cast<const float4*>(&buf[wave][h * Dv + cb + 256 * j]);
                acc[h][j].x += v.x; acc[h][j].y += v.y; acc[h][j].z += v.z; acc[h][j].w += v.w;
            }
    }
    __syncthreads();
    if (wave == 1) {
#pragma unroll
        for (int h = 0; h < NH; ++h)
#pragma unroll
            for (int j = 0; j < 3; ++j)
                *reinterpret_cast<float4*>(&buf[0][h * Dv + cb + 256 * j]) = acc[h][j];
    }
    __syncthreads();
    if (wave == 0) {
#pragma unroll
        for (int h = 0; h < NH; ++h) {
            float inv = 1.f / L[h];
#pragma unroll
            for (int j = 0; j < 3; ++j) {
                float4 v = *reinterpret_cast<const float4*>(&buf[0][h * Dv + cb + 256 * j]);
                float4 r;
                r.x = (acc[h][j].x + v.x) * inv;
                r.y = (acc[h][j].y + v.y) * inv;
                r.z = (acc[h][j].z + v.z) * inv;
                r.w = (acc[h][j].w + v.w) * inv;
                *reinterpret_cast<float4*>(&outp[(size_t)b * NH * Dv + h * Dv + cb + 256 * j]) = r;
            }
        }
    }
}

// ---------------------------------------------------------------------------
// GEMM, W transposed-access: out[m,n] = bias[n] + sum_k A[m,k]*W[n,k]
// BM=64, BK=16, BN templated (64 or 32). headsel: A row base offset =
// (n0/96)*768 (for o = W_v * xw[b, head(n)]).
// ---------------------------------------------------------------------------
template<int BN>
__global__ __launch_bounds__(256)
void gemm_wt(const float* __restrict__ A, int lda,
             const float* __restrict__ W, int ldw,
             const float* __restrict__ bias,
             float* __restrict__ outp, int ldo,
             int K, int headsel)
{
    constexpr int TM = (BN == 64) ? 4 : 2;
    __shared__ float As[16][68];
    __shared__ float Bs[16][BN + 4];
    const int t  = threadIdx.x;
    const int n0 = blockIdx.x * BN;
    const int m0 = blockIdx.y * 64;
    const float* Ab = A + (size_t)m0 * lda + (headsel ? (size_t)(n0 / DHv) * Dv : 0);
    const float* Wb = W + (size_t)n0 * ldw;
    const int tc = (BN == 64) ? (t & 15) : (t & 7);
    const int tr = (BN == 64) ? (t >> 4) : (t >> 3);
    float acc[TM][4];
#pragma unroll
    for (int i = 0; i < TM; ++i)
#pragma unroll
        for (int j = 0; j < 4; ++j) acc[i][j] = 0.f;
    const int arow = t >> 2, akq = t & 3;
    for (int kt = 0; kt < K; kt += 16) {
        __syncthreads();
        float4 a4 = ld4(Ab + (size_t)arow * lda + kt + akq * 4);
        As[akq * 4 + 0][arow] = a4.x; As[akq * 4 + 1][arow] = a4.y;
        As[akq * 4 + 2][arow] = a4.z; As[akq * 4 + 3][arow] = a4.w;
        if (BN == 64 || t < 128) {
            float4 b4 = ld4(Wb + (size_t)arow * ldw + kt + akq * 4);
            Bs[akq * 4 + 0][arow] = b4.x; Bs[akq * 4 + 1][arow] = b4.y;
            Bs[akq * 4 + 2][arow] = b4.z; Bs[akq * 4 + 3][arow] = b4.w;
        }
        __syncthreads();
#pragma unroll
        for (int kk = 0; kk < 16; ++kk) {
            float av[TM], bv[4];
#pragma unroll
            for (int i = 0; i < TM; ++i) av[i] = As[kk][tr * TM + i];
#pragma unroll
            for (int j = 0; j < 4; ++j) bv[j] = Bs[kk][tc * 4 + j];
#pragma unroll
            for (int i = 0; i < TM; ++i)
#pragma unroll
                for (int j = 0; j < 4; ++j) acc[i][j] = fmaf(av[i], bv[j], acc[i][j]);
        }
    }
#pragma unroll
    for (int i = 0; i < TM; ++i)
#pragma unroll
        for (int j = 0; j < 4; ++j)
            outp[(size_t)(m0 + tr * TM + i) * ldo + n0 + tc * 4 + j] =
                acc[i][j] + bias[n0 + tc * 4 + j];
}

// ---------------------------------------------------------------------------
// Qk[b,h,n] = sum_{j<96} q[b, h*96+j] * w_k[h*96+j, n]   (W is k-major)
// ---------------------------------------------------------------------------
__global__ __launch_bounds__(256)
void gemm_wn(const float* __restrict__ A,   // q (256,768)
             const float* __restrict__ W,   // w_k[t] (768,768)
             float* __restrict__ outp)      // Qk (256,8,768)
{
    __shared__ float As[16][68];
    __shared__ float Bs[16][68];
    const int t  = threadIdx.x;
    const int n0 = blockIdx.x * 64;
    const int m0 = blockIdx.y * 64;
    const int h  = blockIdx.z;
    const float* Ab = A + (size_t)m0 * Dv + h * DHv;
    const float* Wb = W + (size_t)h * DHv * Dv + n0;
    const int tc = t & 15, tr = t >> 4;
    float acc[4][4];
#pragma unroll
    for (int i = 0; i < 4; ++i)
#pragma unroll
        for (int j = 0; j < 4; ++j) acc[i][j] = 0.f;
    const int arow = t >> 2, akq = t & 3;
    const int brow = t >> 4, bq = t & 15;
    for (int kt = 0; kt < DHv; kt += 16) {
        __syncthreads();
        float4 a4 = ld4(Ab + (size_t)arow * Dv + kt + akq * 4);
        float4 b4 = ld4(Wb + (size_t)(kt + brow) * Dv + bq * 4);
        As[akq * 4 + 0][arow] = a4.x; As[akq * 4 + 1][arow] = a4.y;
        As[akq * 4 + 2][arow] = a4.z; As[akq * 4 + 3][arow] = a4.w;
        *reinterpret_cast<float4*>(&Bs[brow][bq * 4]) = b4;
        __syncthreads();
#pragma unroll
        for (int kk = 0; kk < 16; ++kk) {
            float av[4], bv[4];
#pragma unroll
            for (int i = 0; i < 4; ++i) av[i] = As[kk][tr * 4 + i];
#pragma unroll
            for (int j = 0; j < 4; ++j) bv[j] = Bs[kk][tc * 4 + j];
#pragma unroll
            for (int i = 0; i < 4; ++i)
#pragma unroll
                for (int j = 0; j < 4; ++j) acc[i][j] = fmaf(av[i], bv[j], acc[i][j]);
        }
    }
#pragma unroll
    for (int i = 0; i < 4; ++i)
#pragma unroll
        for (int j = 0; j < 4; ++j)
            outp[(size_t)(m0 + tr * 4 + i) * (Hv * Dv) + h * Dv + n0 + tc * 4 + j] = acc[i][j];
}

// ---------------------------------------------------------------------------
// Precompute 1: twiddle tables (blocks 0..47) + filt means (blocks 48..111)
// ---------------------------------------------------------------------------
__global__ __launch_bounds__(256)
void pre1_kernel(float* __restrict__ twc, float* __restrict__ tws,
                 const float* __restrict__ sr, const float* __restrict__ si,
                 float* __restrict__ filt)
{
    __shared__ float red[8];
    const int bid = blockIdx.x;
    if (bid < 48) {
        int idx = bid * 256 + threadIdx.x;      // 0..12287
        int k = idx / Dv, n = idx % Dv;
        int r = (k * n) % Dv;
        float ang = (float)r * (float)(6.283185307179586 / 768.0);
        twc[idx] = cosf(ang);
        tws[idx] = sinf(ang);
    } else {
        int tk = bid - 48;                      // t*16+k, 0..63
        const float* a  = sr + (size_t)tk * Dv;
        const float* b2 = si + (size_t)tk * Dv;
        float s1 = 0.f, s2 = 0.f;
#pragma unroll
        for (int j = 0; j < 3; ++j) {
            int c = threadIdx.x + 256 * j;
            s1 += a[c]; s2 += b2[c];
        }
        int wave = threadIdx.x >> 6, lane = threadIdx.x & 63;
#pragma unroll
        for (int dd = 1; dd < 64; dd <<= 1) { s1 += __shfl_xor(s1, dd); s2 += __shfl_xor(s2, dd); }
        if (lane == 0) { red[wave * 2] = s1; red[wave * 2 + 1] = s2; }
        __syncthreads();
        if (threadIdx.x == 0) {
            filt[tk * 2]     = (red[0] + red[2] + red[4] + red[6]) * (1.f / 768.f);
            filt[tk * 2 + 1] = (red[1] + red[3] + red[5] + red[7]) * (1.f / 768.f);
        }
    }
}

// ---------------------------------------------------------------------------
// Precompute 2: C[t,k,i] = (1/768) sum_n proj_w[t][i,n] cos(2pi k n/768); S sin
// ---------------------------------------------------------------------------
__global__ __launch_bounds__(256)
void cs_kernel(const float* __restrict__ proj_w, const float* __restrict__ twc,
               const float* __restrict__ tws, float* __restrict__ csC,
               float* __restrict__ csS)
{
    const int i = blockIdx.x * 256 + threadIdx.x;   // 0..767
    const int k = blockIdx.y;
    const int t = blockIdx.z;
    const float* pr = proj_w + ((size_t)t * Dv + i) * Dv;
    const float* tc = twc + (size_t)k * Dv;
    const float* ts = tws + (size_t)k * Dv;
    float ac = 0.f, as = 0.f;
    for (int n = 0; n < Dv; ++n) {
        float p = pr[n];
        ac = fmaf(p, tc[n], ac);
        as = fmaf(p, ts[n], as);
    }
    csC[((size_t)t * 16 + k) * Dv + i] = ac * (1.f / 768.f);
    csS[((size_t)t * 16 + k) * Dv + i] = as * (1.f / 768.f);
}

// ---------------------------------------------------------------------------
// z1 = LN(z + sa*z_attn); keep[b,k] = filt_k * DFT_k(z1), k<16
// ---------------------------------------------------------------------------
__global__ __launch_bounds__(256)
void ln1_dft_kernel(const float* __restrict__ z, const float* __restrict__ za,
                    const float* __restrict__ g1, const float* __restrict__ b1,
                    const float* __restrict__ sa_p,
                    const float* __restrict__ twc, const float* __restrict__ tws,
                    const float* __restrict__ filt_t,
                    float* __restrict__ z1, float* __restrict__ keep)
{
    const int b = blockIdx.x, tid = threadIdx.x;
    const int wave = tid >> 6, lane = tid & 63;
    __shared__ float red[8];
    __shared__ float dred[4][32];
    __shared__ float fin[32];
    const float sa = sa_p[0];
    float v[3]; float s = 0.f, s2 = 0.f;
#pragma unroll
    for (int j = 0; j < 3; ++j) {
        int c = tid + 256 * j;
        float val = z[(size_t)b * Dv + c] + sa * za[(size_t)b * Dv + c];
        v[j] = val; s += val; s2 += val * val;
    }
#pragma unroll
    for (int dd = 1; dd < 64; dd <<= 1) { s += __shfl_xor(s, dd); s2 += __shfl_xor(s2, dd); }
    if (lane == 0) { red[wave * 2] = s; red[wave * 2 + 1] = s2; }
    __syncthreads();
    const float mean = (red[0] + red[2] + red[4] + red[6]) * (1.f / 768.f);
    const float var  = (red[1] + red[3] + red[5] + red[7]) * (1.f / 768.f) - mean * mean;
    const float rstd = rsqrtf(var + 1e-5f);
    float zv[3];
#pragma unroll
    for (int j = 0; j < 3; ++j) {
        int c = tid + 256 * j;
        float val = (v[j] - mean) * rstd * g1[c] + b1[c];
        zv[j] = val;
        z1[(size_t)b * Dv + c] = val;
    }
    float Fc[16], Fs[16];
#pragma unroll
    for (int k = 0; k < 16; ++k) { Fc[k] = 0.f; Fs[k] = 0.f; }
#pragma unroll
    for (int j = 0; j < 3; ++j) {
        int c = tid + 256 * j;
#pragma unroll
        for (int k = 0; k < 16; ++k) {
            Fc[k] = fmaf(zv[j], twc[k * Dv + c], Fc[k]);
            Fs[k] = fmaf(zv[j], tws[k * Dv + c], Fs[k]);
        }
    }
#pragma unroll
    for (int dd = 1; dd < 64; dd <<= 1) {
#pragma unroll
        for (int k = 0; k < 16; ++k) { Fc[k] += __shfl_xor(Fc[k], dd); Fs[k] += __shfl_xor(Fs[k], dd); }
    }
    if (lane == 0) {
#pragma unroll
        for (int k = 0; k < 16; ++k) { dred[wave][k] = Fc[k]; dred[wave][16 + k] = Fs[k]; }
    }
    __syncthreads();
    if (tid < 32) fin[tid] = dred[0][tid] + dred[1][tid] + dred[2][tid] + dred[3][tid];
    __syncthreads();
    if (tid < 16) {
        float Sc = fin[tid], Ss = fin[16 + tid];   // fft_k = Sc - i*Ss
        float fr = filt_t[tid * 2], fi = filt_t[tid * 2 + 1];
        keep[(size_t)b * 32 + tid * 2]     = Sc * fr + Ss * fi;
        keep[(size_t)b * 32 + tid * 2 + 1] = Sc * fi - Ss * fr;
    }
}

// ---------------------------------------------------------------------------
// z_den from keep via folded C/S; z2 = LN(z1 + sd*z_den); z3 = g*z2+(1-g)*z;
// z = bn(z3); out += 0.25 * classify(z)
// ---------------------------------------------------------------------------
__global__ __launch_bounds__(256)
void den_cls_kernel(const float* __restrict__ keep, const float* __restrict__ csC_t,
                    const float* __restrict__ csS_t, const float* __restrict__ pb_t,
                    const float* __restrict__ z1, float* __restrict__ z,
                    const float* __restrict__ g2, const float* __restrict__ b2,
                    const float* __restrict__ bng, const float* __restrict__ bnb,
                    const float* __restrict__ gate_p, const float* __restrict__ sd_p,
                    const float* __restrict__ f1w, const float* __restrict__ f1b,
                    const float* __restrict__ f1g, const float* __restrict__ f1bb,
                    const float* __restrict__ f2w, const float* __restrict__ f2b,
                    const float* __restrict__ f2g, const float* __restrict__ f2bb,
                    const float* __restrict__ clw, const float* __restrict__ clb,
                    float* __restrict__ outp, int t)
{
    const int b = blockIdx.x, tid = threadIdx.x;
    const int wave = tid >> 6, lane = tid & 63;
    __shared__ float kr[16], ki[16];
    __shared__ float zs[768];
    __shared__ float h1s[256];
    __shared__ float h2s[128];
    __shared__ float red[8];
    if (tid < 16) { kr[tid] = keep[(size_t)b * 32 + tid * 2]; ki[tid] = keep[(size_t)b * 32 + tid * 2 + 1]; }
    __syncthreads();
    const float sd  = sd_p[0];
    const float gv  = 1.f / (1.f + expf(-gate_p[0]));
    const float bnc = 1.f / sqrtf(1.f + 1e-5f);
    float v[3]; float s = 0.f, s2 = 0.f;
#pragma unroll
    for (int j = 0; j < 3; ++j) {
        int c = tid + 256 * j;
        float den = pb_t[c];
#pragma unroll
        for (int k = 0; k < 16; ++k) {
            den = fmaf(kr[k], csC_t[k * Dv + c], den);
            den = fmaf(-ki[k], csS_t[k * Dv + c], den);
        }
        float val = z1[(size_t)b * Dv + c] + sd * den;
        v[j] = val; s += val; s2 += val * val;
    }
#pragma unroll
    for (int dd = 1; dd < 64; dd <<= 1) { s += __shfl_xor(s, dd); s2 += __shfl_xor(s2, dd); }
    if (lane == 0) { red[wave * 2] = s; red[wave * 2 + 1] = s2; }
    __syncthreads();
    const float mean = (red[0] + red[2] + red[4] + red[6]) * (1.f / 768.f);
    const float var  = (red[1] + red[3] + red[5] + red[7]) * (1.f / 768.f) - mean * mean;
    const float rstd = rsqrtf(var + 1e-5f);
#pragma unroll
    for (int j = 0; j < 3; ++j) {
        int c = tid + 256 * j;
        float z2v = (v[j] - mean) * rstd * g2[c] + b2[c];
        float z3v = gv * z2v + (1.f - gv) * z[(size_t)b * Dv + c];
        float zn  = z3v * (bng[c] * bnc) + bnb[c];
        z[(size_t)b * Dv + c] = zn;
        zs[c] = zn;
    }
    __syncthreads();
    // f1: 768 -> 256
    float h = f1b[tid];
    for (int d = 0; d < 768; ++d) h = fmaf(zs[d], f1w[(size_t)d * 256 + tid], h);
    h = h * (f1g[tid] * bnc) + f1bb[tid];
    h1s[tid] = fmaxf(h, 0.f);
    __syncthreads();
    if (tid < 128) {
        float h2 = f2b[tid];
        for (int i2 = 0; i2 < 256; ++i2) h2 = fmaf(h1s[i2], f2w[(size_t)i2 * 128 + tid], h2);
        h2 = h2 * (f2g[tid] * bnc) + f2bb[tid];
        h2s[tid] = fmaxf(h2, 0.f);
    }
    __syncthreads();
    if (tid < NCv) {
        float lg = clb[tid];
        for (int i2 = 0; i2 < 128; ++i2) lg = fmaf(h2s[i2], clw[(size_t)i2 * NCv + tid], lg);
        lg *= 0.25f;
        if (t == 0) outp[(size_t)b * NCv + tid] = lg;
        else        outp[(size_t)b * NCv + tid] += lg;
    }
}

// ---------------------------------------------------------------------------
extern "C" void kernel_launch(void* const* d_in, const int* in_sizes, int n_in,
                              void* d_out, int out_size, void* d_ws, size_t ws_size,
                              hipStream_t stream)
{
    (void)in_sizes; (void)n_in; (void)out_size; (void)ws_size;
    const float* x      = (const float*)d_in[0];
    const float* pool_w = (const float*)d_in[1];
    // d_in[2] pool_b: constant shift under softmax -> dropped
    const float* w_q   = (const float*)d_in[3];
    const float* w_k   = (const float*)d_in[4];
    const float* w_v   = (const float*)d_in[5];
    const float* b_qkv = (const float*)d_in[6];
    const float* w_o   = (const float*)d_in[7];
    const float* b_o   = (const float*)d_in[8];
    const float* ln1_g = (const float*)d_in[9];
    const float* ln1_b = (const float*)d_in[10];
    const float* ln2_g = (const float*)d_in[11];
    const float* ln2_b = (const float*)d_in[12];
    const float* s_re  = (const float*)d_in[13];
    const float* s_im  = (const float*)d_in[14];
    const float* proj_w= (const float*)d_in[15];
    const float* proj_b= (const float*)d_in[16];
    const float* bn_g  = (const float*)d_in[17];
    const float* bn_b  = (const float*)d_in[18];
    const float* gate  = (const float*)d_in[19];
    const float* s_at  = (const float*)d_in[20];
    const float* s_dn  = (const float*)d_in[21];
    const float* f1w   = (const float*)d_in[22];
    const float* f1b   = (const float*)d_in[23];
    const float* f1g   = (const float*)d_in[24];
    const float* f1bb  = (const float*)d_in[25];
    const float* f2w   = (const float*)d_in[26];
    const float* f2b   = (const float*)d_in[27];
    const float* f2g   = (const float*)d_in[28];
    const float* f2bb  = (const float*)d_in[29];
    const float* clw   = (const float*)d_in[30];
    const float* clb   = (const float*)d_in[31];
    float* out = (float*)d_out;
    float* ws  = (float*)d_ws;

    // ws layout (floats): total ~4.26M (~17 MB)
    float* twc  = ws;               // 16*768
    float* tws  = twc + 12288;      // 16*768
    float* filt = tws + 12288;      // 4*16*2
    float* csC  = filt + 128;       // 4*16*768
    float* csS  = csC + 49152;      // 4*16*768
    float* z    = csS + 49152;      // 256*768
    float* q    = z   + 196608;     // 256*768
    float* Qk   = q   + 196608;     // 256*8*768
    float* xw   = Qk  + 1572864;    // 256*8*768
    float* o    = xw  + 1572864;    // 256*768
    float* za   = o   + 196608;     // 256*768
    float* z1   = za  + 196608;     // 256*768
    float* keep = z1  + 196608;     // 256*16*2

    pre1_kernel<<<112, 256, 0, stream>>>(twc, tws, s_re, s_im, filt);
    cs_kernel<<<dim3(3, 16, 4), 256, 0, stream>>>(proj_w, twc, tws, csC, csS);

    // pooling: z[b] = softmax_s(x . pool_w) weighted sum of x
    flash_kernel<1><<<256, 512, 0, stream>>>(x, pool_w, z, 1.0f);

    const float iscale = (float)(1.0 / sqrt(96.0));
    for (int t = 0; t < 4; ++t) {
        const size_t dd = (size_t)t * Dv * Dv;
        // q = z @ w_q^T + bq
        gemm_wt<64><<<dim3(12, 4), 256, 0, stream>>>(z, Dv, w_q + dd, Dv,
                                                     b_qkv + (size_t)t * 3 * Dv, q, Dv, Dv, 0);
        // Qk[b,h,:] = W_k_h^T q_h
        gemm_wn<<<dim3(12, 4, 8), 256, 0, stream>>>(q, w_k + dd, Qk);
        // xw[b,h,:] = softmax_s(Qk.x/sqrt(DH)) weighted sum of x
        flash_kernel<8><<<256, 512, 0, stream>>>(x, Qk, xw, iscale);
        // o = W_v xw(head) + bv
        gemm_wt<32><<<dim3(24, 4), 256, 0, stream>>>(xw, Hv * Dv, w_v + dd, Dv,
                                                     b_qkv + (size_t)t * 3 * Dv + 2 * Dv, o, Dv, Dv, 1);
        // z_attn = o @ w_o^T + b_o
        gemm_wt<64><<<dim3(12, 4), 256, 0, stream>>>(o, Dv, w_o + dd, Dv,
                                                     b_o + (size_t)t * Dv, za, Dv, Dv, 0);
        // z1 = LN(z + sa*z_attn), keep = filt * DFT16(z1)
        ln1_dft_kernel<<<256, 256, 0, stream>>>(z, za, ln1_g + (size_t)t * Dv, ln1_b + (size_t)t * Dv,
                                                s_at + t, twc, tws, filt + (size_t)t * 32, z1, keep);
        // z_den -> z2 -> z3 -> bn -> z ; out += 0.25*classify(z)
        den_cls_kernel<<<256, 256, 0, stream>>>(keep, csC + (size_t)t * 16 * Dv, csS + (size_t)t * 16 * Dv,
                                                proj_b + (size_t)t * Dv, z1, z,
                                                ln2_g + (size_t)t * Dv, ln2_b + (size_t)t * Dv,
                                                bn_g + (size_t)t * Dv, bn_b + (size_t)t * Dv,
                                                gate + t, s_dn + t,
                                                f1w, f1b, f1g, f1bb, f2w, f2b, f2g, f2bb,
                                                clw, clb, out, t);
    }
}

// Round 2
// 1515.817 us; speedup vs baseline: 1.9492x; 1.9492x over previous
//
#include <hip/hip_runtime.h>
#include <math.h>

// ---------------------------------------------------------------------------
// NoPropDTEncoder forward, restructured:
//  - pooling + 4 attention stages as 1-pass online-softmax streams over x_feat
//  - attention flash: LDS-staged x tiles, wave-per-head, counted-vmcnt pipeline
//  - FFT branch: only modes 0..15 matter; ifft+proj folded into C/S matrices
//  - small fp32 tiled GEMMs for q / Qk / o / z_attn
// ---------------------------------------------------------------------------

#define DEV __device__ __forceinline__

constexpr int Bv  = 256;
constexpr int Sv  = 512;
constexpr int Dv  = 768;
constexpr int Hv  = 8;
constexpr int DHv = 96;
constexpr int NCv = 14;

DEV float4 ld4(const float* p) { return *reinterpret_cast<const float4*>(p); }

// ---------------------------------------------------------------------------
// Pooling flash pass (NH=1): one block per b, 8 waves x 64 rows, register
// double-buffer. Low register pressure at NH=1 -> no spill.
// ---------------------------------------------------------------------------
template<int NH>
__global__ __launch_bounds__(512, 2)
void flash_kernel(const float* __restrict__ x,    // (B,S,D)
                  const float* __restrict__ qk,   // NH==1: (D) shared
                  float* __restrict__ outp,       // (B,NH,D)
                  float scale)
{
    __shared__ float qks[NH * Dv];
    __shared__ float buf[4][NH * Dv];
    __shared__ float mlb[8][NH][2];

    const int b    = blockIdx.x;
    const int tid  = threadIdx.x;
    const int wave = tid >> 6;
    const int lane = tid & 63;

    const float* qsrc = (NH == 1) ? qk : (qk + (size_t)b * NH * Dv);
    for (int v4 = tid; v4 < NH * (Dv / 4); v4 += 512) {
        *reinterpret_cast<float4*>(&qks[v4 * 4]) = ld4(qsrc + v4 * 4);
    }
    __syncthreads();

    float4 acc[NH][3];
    float m[NH], l[NH];
#pragma unroll
    for (int h = 0; h < NH; ++h) {
        m[h] = -INFINITY; l[h] = 0.f;
#pragma unroll
        for (int j = 0; j < 3; ++j) acc[h][j] = make_float4(0.f, 0.f, 0.f, 0.f);
    }

    const int s0 = wave * 64;
    const float* base = x + ((size_t)b * Sv + s0) * Dv + 4 * lane;

    float4 c0[3], c1[3];
#pragma unroll
    for (int j = 0; j < 3; ++j) { c0[j] = ld4(base + 256 * j); c1[j] = ld4(base + Dv + 256 * j); }

    for (int it = 0; it < 32; ++it) {
        float4 nx0[3], nx1[3];
        if (it < 31) {
            const float* nb = base + (size_t)(2 * it + 2) * Dv;
#pragma unroll
            for (int j = 0; j < 3; ++j) { nx0[j] = ld4(nb + 256 * j); nx1[j] = ld4(nb + Dv + 256 * j); }
        }
        float p0[NH], p1[NH];
#pragma unroll
        for (int h = 0; h < NH; ++h) {
            float a0 = 0.f, a1 = 0.f;
#pragma unroll
            for (int j = 0; j < 3; ++j) {
                const float4 q4 = *reinterpret_cast<const float4*>(&qks[h * Dv + 4 * lane + 256 * j]);
                a0 = fmaf(q4.x, c0[j].x, a0); a0 = fmaf(q4.y, c0[j].y, a0);
                a0 = fmaf(q4.z, c0[j].z, a0); a0 = fmaf(q4.w, c0[j].w, a0);
                a1 = fmaf(q4.x, c1[j].x, a1); a1 = fmaf(q4.y, c1[j].y, a1);
                a1 = fmaf(q4.z, c1[j].z, a1); a1 = fmaf(q4.w, c1[j].w, a1);
            }
            p0[h] = a0; p1[h] = a1;
        }
#pragma unroll
        for (int dd = 1; dd < 64; dd <<= 1) {
#pragma unroll
            for (int h = 0; h < NH; ++h) {
                p0[h] += __shfl_xor(p0[h], dd);
                p1[h] += __shfl_xor(p1[h], dd);
            }
        }
#pragma unroll
        for (int h = 0; h < NH; ++h) {
            float sc0 = p0[h] * scale, sc1 = p1[h] * scale;
            float mx = fmaxf(sc0, sc1);
            if (mx > m[h]) {
                float r = expf(m[h] - mx);
                l[h] *= r;
#pragma unroll
                for (int j = 0; j < 3; ++j) {
                    acc[h][j].x *= r; acc[h][j].y *= r; acc[h][j].z *= r; acc[h][j].w *= r;
                }
                m[h] = mx;
            }
            float w0 = expf(sc0 - m[h]);
            float w1 = expf(sc1 - m[h]);
            l[h] += w0 + w1;
#pragma unroll
            for (int j = 0; j < 3; ++j) {
                acc[h][j].x = fmaf(w1, c1[j].x, fmaf(w0, c0[j].x, acc[h][j].x));
                acc[h][j].y = fmaf(w1, c1[j].y, fmaf(w0, c0[j].y, acc[h][j].y));
                acc[h][j].z = fmaf(w1, c1[j].z, fmaf(w0, c0[j].z, acc[h][j].z));
                acc[h][j].w = fmaf(w1, c1[j].w, fmaf(w0, c0[j].w, acc[h][j].w));
            }
        }
        if (it < 31) {
#pragma unroll
            for (int j = 0; j < 3; ++j) { c0[j] = nx0[j]; c1[j] = nx1[j]; }
        }
    }

    if (lane == 0) {
#pragma unroll
        for (int h = 0; h < NH; ++h) { mlb[wave][h][0] = m[h]; mlb[wave][h][1] = l[h]; }
    }
    __syncthreads();
    float L[NH];
#pragma unroll
    for (int h = 0; h < NH; ++h) {
        float g_ = mlb[0][h][0];
#pragma unroll
        for (int w = 1; w < 8; ++w) g_ = fmaxf(g_, mlb[w][h][0]);
        float Ls = 0.f;
#pragma unroll
        for (int w = 0; w < 8; ++w) Ls += mlb[w][h][1] * expf(mlb[w][h][0] - g_);
        L[h] = Ls;
        float f = expf(m[h] - g_);
#pragma unroll
        for (int j = 0; j < 3; ++j) {
            acc[h][j].x *= f; acc[h][j].y *= f; acc[h][j].z *= f; acc[h][j].w *= f;
        }
    }
    const int cb = 4 * lane;
    if (wave >= 4) {
#pragma unroll
        for (int h = 0; h < NH; ++h)
#pragma unroll
            for (int j = 0; j < 3; ++j)
                *reinterpret_cast<float4*>(&buf[wave - 4][h * Dv + cb + 256 * j]) = acc[h][j];
    }
    __syncthreads();
    if (wave < 4) {
#pragma unroll
        for (int h = 0; h < NH; ++h)
#pragma unroll
            for (int j = 0; j < 3; ++j) {
                float4 v = *reinterpret_cast<const float4*>(&buf[wave][h * Dv + cb + 256 * j]);
                acc[h][j].x += v.x; acc[h][j].y += v.y; acc[h][j].z += v.z; acc[h][j].w += v.w;
            }
    }
    __syncthreads();
    if (wave == 2 || wave == 3) {
#pragma unroll
        for (int h = 0; h < NH; ++h)
#pragma unroll
            for (int j = 0; j < 3; ++j)
                *reinterpret_cast<float4*>(&buf[wave - 2][h * Dv + cb + 256 * j]) = acc[h][j];
    }
    __syncthreads();
    if (wave < 2) {
#pragma unroll
        for (int h = 0; h < NH; ++h)
#pragma unroll
            for (int j = 0; j < 3; ++j) {
                float4 v = *reinterpret_cast<const float4*>(&buf[wave][h * Dv + cb + 256 * j]);
                acc[h][j].x += v.x; acc[h][j].y += v.y; acc[h][j].z += v.z; acc[h][j].w += v.w;
            }
    }
    __syncthreads();
    if (wave == 1) {
#pragma unroll
        for (int h = 0; h < NH; ++h)
#pragma unroll
            for (int j = 0; j < 3; ++j)
                *reinterpret_cast<float4*>(&buf[0][h * Dv + cb + 256 * j]) = acc[h][j];
    }
    __syncthreads();
    if (wave == 0) {
#pragma unroll
        for (int h = 0; h < NH; ++h) {
            float inv = 1.f / L[h];
#pragma unroll
            for (int j = 0; j < 3; ++j) {
                float4 v = *reinterpret_cast<const float4*>(&buf[0][h * Dv + cb + 256 * j]);
                float4 r;
                r.x = (acc[h][j].x + v.x) * inv;
                r.y = (acc[h][j].y + v.y) * inv;
                r.z = (acc[h][j].z + v.z) * inv;
                r.w = (acc[h][j].w + v.w) * inv;
                *reinterpret_cast<float4*>(&outp[(size_t)b * NH * Dv + h * Dv + cb + 256 * j]) = r;
            }
        }
    }
}

// ---------------------------------------------------------------------------
// Attention flash (8 heads): one block per b, wave w owns head w completely.
// x staged to LDS in 8-row tiles via global_load_lds, double-buffered with
// counted vmcnt + raw s_barrier (loads stay in flight across barriers).
// Each wave reads the tile once from LDS, keeps it in regs for score + accum.
// VGPR ~150 (no spill at launch_bounds(512,1)).
// ---------------------------------------------------------------------------
__global__ __launch_bounds__(512, 1)
void attn_flash_kernel(const float* __restrict__ x,    // (B,S,D)
                       const float* __restrict__ Qk,   // (B,H,D)
                       float* __restrict__ xw,         // (B,H,D)
                       float scale)
{
    __shared__ float xs[2][8 * Dv];   // 2 x 24KB tiles
    const int b    = blockIdx.x;
    const int tid  = threadIdx.x;
    const int wave = tid >> 6;
    const int lane = tid & 63;
    const int col  = 4 * lane;

    // per-wave query (head = wave) hoisted to registers
    float4 qr[3];
#pragma unroll
    for (int j = 0; j < 3; ++j)
        qr[j] = ld4(Qk + ((size_t)b * Hv + wave) * Dv + col + 256 * j);

    float4 acc[3];
#pragma unroll
    for (int j = 0; j < 3; ++j) acc[j] = make_float4(0.f, 0.f, 0.f, 0.f);
    float m = -INFINITY, l = 0.f;

    // stage tile 0 into buf 0
    {
        const float* g = x + ((size_t)b * Sv) * Dv + wave * 256 + lane * 4;
        float* lb = &xs[0][wave * 256];
#pragma unroll
        for (int j = 0; j < 3; ++j)
            __builtin_amdgcn_global_load_lds(
                (const __attribute__((address_space(1))) void*)(g + j * 2048),
                (__attribute__((address_space(3))) void*)(lb + j * 2048), 16, 0, 0);
    }

    int cur = 0;
    for (int i = 0; i < 64; ++i) {
        // everyone done reading xs[cur^1] (prev iter) before we overwrite it
        __builtin_amdgcn_s_barrier();
        if (i < 63) {
            const float* g = x + ((size_t)b * Sv + (size_t)(i + 1) * 8) * Dv + wave * 256 + lane * 4;
            float* lb = &xs[cur ^ 1][wave * 256];
#pragma unroll
            for (int j = 0; j < 3; ++j)
                __builtin_amdgcn_global_load_lds(
                    (const __attribute__((address_space(1))) void*)(g + j * 2048),
                    (__attribute__((address_space(3))) void*)(lb + j * 2048), 16, 0, 0);
            asm volatile("s_waitcnt vmcnt(3)" ::: "memory");   // tile i landed (3 next-tile loads in flight)
        } else {
            asm volatile("s_waitcnt vmcnt(0)" ::: "memory");
        }
        __builtin_amdgcn_s_barrier();                          // all waves' tile-i data visible
        __builtin_amdgcn_sched_barrier(0);

        const float* xt = xs[cur];
        float4 xr[8][3];
        float s8[8];
#pragma unroll
        for (int r = 0; r < 8; ++r) {
            float a = 0.f;
#pragma unroll
            for (int j = 0; j < 3; ++j) {
                xr[r][j] = *reinterpret_cast<const float4*>(&xt[r * Dv + col + 256 * j]);
                a = fmaf(qr[j].x, xr[r][j].x, a);
                a = fmaf(qr[j].y, xr[r][j].y, a);
                a = fmaf(qr[j].z, xr[r][j].z, a);
                a = fmaf(qr[j].w, xr[r][j].w, a);
            }
            s8[r] = a;
        }
#pragma unroll
        for (int d = 1; d < 64; d <<= 1) {
#pragma unroll
            for (int r = 0; r < 8; ++r) s8[r] += __shfl_xor(s8[r], d);
        }
#pragma unroll
        for (int r = 0; r < 8; ++r) s8[r] *= scale;
        float mx = fmaxf(fmaxf(fmaxf(s8[0], s8[1]), fmaxf(s8[2], s8[3])),
                         fmaxf(fmaxf(s8[4], s8[5]), fmaxf(s8[6], s8[7])));
        if (mx > m) {                      // wave-uniform
            float f = __expf(m - mx);      // first tile: __expf(-inf) = 0
            l *= f;
#pragma unroll
            for (int j = 0; j < 3; ++j) { acc[j].x *= f; acc[j].y *= f; acc[j].z *= f; acc[j].w *= f; }
            m = mx;
        }
#pragma unroll
        for (int r = 0; r < 8; ++r) {
            float w = __expf(s8[r] - m);
            l += w;
#pragma unroll
            for (int j = 0; j < 3; ++j) {
                acc[j].x = fmaf(w, xr[r][j].x, acc[j].x);
                acc[j].y = fmaf(w, xr[r][j].y, acc[j].y);
                acc[j].z = fmaf(w, xr[r][j].z, acc[j].z);
                acc[j].w = fmaf(w, xr[r][j].w, acc[j].w);
            }
        }
        cur ^= 1;
    }

    const float invl = 1.f / l;
#pragma unroll
    for (int j = 0; j < 3; ++j) {
        float4 r;
        r.x = acc[j].x * invl; r.y = acc[j].y * invl;
        r.z = acc[j].z * invl; r.w = acc[j].w * invl;
        *reinterpret_cast<float4*>(&xw[((size_t)b * Hv + wave) * Dv + col + 256 * j]) = r;
    }
}

// ---------------------------------------------------------------------------
// GEMM, W transposed-access: out[m,n] = bias[n] + sum_k A[m,k]*W[n,k]
// ---------------------------------------------------------------------------
template<int BN>
__global__ __launch_bounds__(256)
void gemm_wt(const float* __restrict__ A, int lda,
             const float* __restrict__ W, int ldw,
             const float* __restrict__ bias,
             float* __restrict__ outp, int ldo,
             int K, int headsel)
{
    constexpr int TM = (BN == 64) ? 4 : 2;
    __shared__ float As[16][68];
    __shared__ float Bs[16][BN + 4];
    const int t  = threadIdx.x;
    const int n0 = blockIdx.x * BN;
    const int m0 = blockIdx.y * 64;
    const float* Ab = A + (size_t)m0 * lda + (headsel ? (size_t)(n0 / DHv) * Dv : 0);
    const float* Wb = W + (size_t)n0 * ldw;
    const int tc = (BN == 64) ? (t & 15) : (t & 7);
    const int tr = (BN == 64) ? (t >> 4) : (t >> 3);
    float acc[TM][4];
#pragma unroll
    for (int i = 0; i < TM; ++i)
#pragma unroll
        for (int j = 0; j < 4; ++j) acc[i][j] = 0.f;
    const int arow = t >> 2, akq = t & 3;
    for (int kt = 0; kt < K; kt += 16) {
        __syncthreads();
        float4 a4 = ld4(Ab + (size_t)arow * lda + kt + akq * 4);
        As[akq * 4 + 0][arow] = a4.x; As[akq * 4 + 1][arow] = a4.y;
        As[akq * 4 + 2][arow] = a4.z; As[akq * 4 + 3][arow] = a4.w;
        if (BN == 64 || t < 128) {
            float4 b4 = ld4(Wb + (size_t)arow * ldw + kt + akq * 4);
            Bs[akq * 4 + 0][arow] = b4.x; Bs[akq * 4 + 1][arow] = b4.y;
            Bs[akq * 4 + 2][arow] = b4.z; Bs[akq * 4 + 3][arow] = b4.w;
        }
        __syncthreads();
#pragma unroll
        for (int kk = 0; kk < 16; ++kk) {
            float av[TM], bv[4];
#pragma unroll
            for (int i = 0; i < TM; ++i) av[i] = As[kk][tr * TM + i];
#pragma unroll
            for (int j = 0; j < 4; ++j) bv[j] = Bs[kk][tc * 4 + j];
#pragma unroll
            for (int i = 0; i < TM; ++i)
#pragma unroll
                for (int j = 0; j < 4; ++j) acc[i][j] = fmaf(av[i], bv[j], acc[i][j]);
        }
    }
#pragma unroll
    for (int i = 0; i < TM; ++i)
#pragma unroll
        for (int j = 0; j < 4; ++j)
            outp[(size_t)(m0 + tr * TM + i) * ldo + n0 + tc * 4 + j] =
                acc[i][j] + bias[n0 + tc * 4 + j];
}

// ---------------------------------------------------------------------------
// Qk[b,h,n] = sum_{j<96} q[b, h*96+j] * w_k[h*96+j, n]   (W is k-major)
// ---------------------------------------------------------------------------
__global__ __launch_bounds__(256)
void gemm_wn(const float* __restrict__ A,   // q (256,768)
             const float* __restrict__ W,   // w_k[t] (768,768)
             float* __restrict__ outp)      // Qk (256,8,768)
{
    __shared__ float As[16][68];
    __shared__ float Bs[16][68];
    const int t  = threadIdx.x;
    const int n0 = blockIdx.x * 64;
    const int m0 = blockIdx.y * 64;
    const int h  = blockIdx.z;
    const float* Ab = A + (size_t)m0 * Dv + h * DHv;
    const float* Wb = W + (size_t)h * DHv * Dv + n0;
    const int tc = t & 15, tr = t >> 4;
    float acc[4][4];
#pragma unroll
    for (int i = 0; i < 4; ++i)
#pragma unroll
        for (int j = 0; j < 4; ++j) acc[i][j] = 0.f;
    const int arow = t >> 2, akq = t & 3;
    const int brow = t >> 4, bq = t & 15;
    for (int kt = 0; kt < DHv; kt += 16) {
        __syncthreads();
        float4 a4 = ld4(Ab + (size_t)arow * Dv + kt + akq * 4);
        float4 b4 = ld4(Wb + (size_t)(kt + brow) * Dv + bq * 4);
        As[akq * 4 + 0][arow] = a4.x; As[akq * 4 + 1][arow] = a4.y;
        As[akq * 4 + 2][arow] = a4.z; As[akq * 4 + 3][arow] = a4.w;
        *reinterpret_cast<float4*>(&Bs[brow][bq * 4]) = b4;
        __syncthreads();
#pragma unroll
        for (int kk = 0; kk < 16; ++kk) {
            float av[4], bv[4];
#pragma unroll
            for (int i = 0; i < 4; ++i) av[i] = As[kk][tr * 4 + i];
#pragma unroll
            for (int j = 0; j < 4; ++j) bv[j] = Bs[kk][tc * 4 + j];
#pragma unroll
            for (int i = 0; i < 4; ++i)
#pragma unroll
                for (int j = 0; j < 4; ++j) acc[i][j] = fmaf(av[i], bv[j], acc[i][j]);
        }
    }
#pragma unroll
    for (int i = 0; i < 4; ++i)
#pragma unroll
        for (int j = 0; j < 4; ++j)
            outp[(size_t)(m0 + tr * 4 + i) * (Hv * Dv) + h * Dv + n0 + tc * 4 + j] = acc[i][j];
}

// ---------------------------------------------------------------------------
// Precompute 1: twiddle tables (blocks 0..47) + filt means (blocks 48..111)
// ---------------------------------------------------------------------------
__global__ __launch_bounds__(256)
void pre1_kernel(float* __restrict__ twc, float* __restrict__ tws,
                 const float* __restrict__ sr, const float* __restrict__ si,
                 float* __restrict__ filt)
{
    __shared__ float red[8];
    const int bid = blockIdx.x;
    if (bid < 48) {
        int idx = bid * 256 + threadIdx.x;      // 0..12287
        int k = idx / Dv, n = idx % Dv;
        int r = (k * n) % Dv;
        float ang = (float)r * (float)(6.283185307179586 / 768.0);
        twc[idx] = cosf(ang);
        tws[idx] = sinf(ang);
    } else {
        int tk = bid - 48;                      // t*16+k, 0..63
        const float* a  = sr + (size_t)tk * Dv;
        const float* b2 = si + (size_t)tk * Dv;
        float s1 = 0.f, s2 = 0.f;
#pragma unroll
        for (int j = 0; j < 3; ++j) {
            int c = threadIdx.x + 256 * j;
            s1 += a[c]; s2 += b2[c];
        }
        int wave = threadIdx.x >> 6, lane = threadIdx.x & 63;
#pragma unroll
        for (int dd = 1; dd < 64; dd <<= 1) { s1 += __shfl_xor(s1, dd); s2 += __shfl_xor(s2, dd); }
        if (lane == 0) { red[wave * 2] = s1; red[wave * 2 + 1] = s2; }
        __syncthreads();
        if (threadIdx.x == 0) {
            filt[tk * 2]     = (red[0] + red[2] + red[4] + red[6]) * (1.f / 768.f);
            filt[tk * 2 + 1] = (red[1] + red[3] + red[5] + red[7]) * (1.f / 768.f);
        }
    }
}

// ---------------------------------------------------------------------------
// Precompute 2: C[t,k,i] = (1/768) sum_n proj_w[t][i,n] cos(2pi k n/768); S sin
// ---------------------------------------------------------------------------
__global__ __launch_bounds__(256)
void cs_kernel(const float* __restrict__ proj_w, const float* __restrict__ twc,
               const float* __restrict__ tws, float* __restrict__ csC,
               float* __restrict__ csS)
{
    const int i = blockIdx.x * 256 + threadIdx.x;   // 0..767
    const int k = blockIdx.y;
    const int t = blockIdx.z;
    const float* pr = proj_w + ((size_t)t * Dv + i) * Dv;
    const float* tc = twc + (size_t)k * Dv;
    const float* ts = tws + (size_t)k * Dv;
    float ac = 0.f, as = 0.f;
    for (int n = 0; n < Dv; ++n) {
        float p = pr[n];
        ac = fmaf(p, tc[n], ac);
        as = fmaf(p, ts[n], as);
    }
    csC[((size_t)t * 16 + k) * Dv + i] = ac * (1.f / 768.f);
    csS[((size_t)t * 16 + k) * Dv + i] = as * (1.f / 768.f);
}

// ---------------------------------------------------------------------------
// z1 = LN(z + sa*z_attn); keep[b,k] = filt_k * DFT_k(z1), k<16
// ---------------------------------------------------------------------------
__global__ __launch_bounds__(256)
void ln1_dft_kernel(const float* __restrict__ z, const float* __restrict__ za,
                    const float* __restrict__ g1, const float* __restrict__ b1,
                    const float* __restrict__ sa_p,
                    const float* __restrict__ twc, const float* __restrict__ tws,
                    const float* __restrict__ filt_t,
                    float* __restrict__ z1, float* __restrict__ keep)
{
    const int b = blockIdx.x, tid = threadIdx.x;
    const int wave = tid >> 6, lane = tid & 63;
    __shared__ float red[8];
    __shared__ float dred[4][32];
    __shared__ float fin[32];
    const float sa = sa_p[0];
    float v[3]; float s = 0.f, s2 = 0.f;
#pragma unroll
    for (int j = 0; j < 3; ++j) {
        int c = tid + 256 * j;
        float val = z[(size_t)b * Dv + c] + sa * za[(size_t)b * Dv + c];
        v[j] = val; s += val; s2 += val * val;
    }
#pragma unroll
    for (int dd = 1; dd < 64; dd <<= 1) { s += __shfl_xor(s, dd); s2 += __shfl_xor(s2, dd); }
    if (lane == 0) { red[wave * 2] = s; red[wave * 2 + 1] = s2; }
    __syncthreads();
    const float mean = (red[0] + red[2] + red[4] + red[6]) * (1.f / 768.f);
    const float var  = (red[1] + red[3] + red[5] + red[7]) * (1.f / 768.f) - mean * mean;
    const float rstd = rsqrtf(var + 1e-5f);
    float zv[3];
#pragma unroll
    for (int j = 0; j < 3; ++j) {
        int c = tid + 256 * j;
        float val = (v[j] - mean) * rstd * g1[c] + b1[c];
        zv[j] = val;
        z1[(size_t)b * Dv + c] = val;
    }
    float Fc[16], Fs[16];
#pragma unroll
    for (int k = 0; k < 16; ++k) { Fc[k] = 0.f; Fs[k] = 0.f; }
#pragma unroll
    for (int j = 0; j < 3; ++j) {
        int c = tid + 256 * j;
#pragma unroll
        for (int k = 0; k < 16; ++k) {
            Fc[k] = fmaf(zv[j], twc[k * Dv + c], Fc[k]);
            Fs[k] = fmaf(zv[j], tws[k * Dv + c], Fs[k]);
        }
    }
#pragma unroll
    for (int dd = 1; dd < 64; dd <<= 1) {
#pragma unroll
        for (int k = 0; k < 16; ++k) { Fc[k] += __shfl_xor(Fc[k], dd); Fs[k] += __shfl_xor(Fs[k], dd); }
    }
    if (lane == 0) {
#pragma unroll
        for (int k = 0; k < 16; ++k) { dred[wave][k] = Fc[k]; dred[wave][16 + k] = Fs[k]; }
    }
    __syncthreads();
    if (tid < 32) fin[tid] = dred[0][tid] + dred[1][tid] + dred[2][tid] + dred[3][tid];
    __syncthreads();
    if (tid < 16) {
        float Sc = fin[tid], Ss = fin[16 + tid];   // fft_k = Sc - i*Ss
        float fr = filt_t[tid * 2], fi = filt_t[tid * 2 + 1];
        keep[(size_t)b * 32 + tid * 2]     = Sc * fr + Ss * fi;
        keep[(size_t)b * 32 + tid * 2 + 1] = Sc * fi - Ss * fr;
    }
}

// ---------------------------------------------------------------------------
// z_den from keep via folded C/S; z2 = LN(z1 + sd*z_den); z3 = g*z2+(1-g)*z;
// z = bn(z3); out += 0.25 * classify(z)
// ---------------------------------------------------------------------------
__global__ __launch_bounds__(256)
void den_cls_kernel(const float* __restrict__ keep, const float* __restrict__ csC_t,
                    const float* __restrict__ csS_t, const float* __restrict__ pb_t,
                    const float* __restrict__ z1, float* __restrict__ z,
                    const float* __restrict__ g2, const float* __restrict__ b2,
                    const float* __restrict__ bng, const float* __restrict__ bnb,
                    const float* __restrict__ gate_p, const float* __restrict__ sd_p,
                    const float* __restrict__ f1w, const float* __restrict__ f1b,
                    const float* __restrict__ f1g, const float* __restrict__ f1bb,
                    const float* __restrict__ f2w, const float* __restrict__ f2b,
                    const float* __restrict__ f2g, const float* __restrict__ f2bb,
                    const float* __restrict__ clw, const float* __restrict__ clb,
                    float* __restrict__ outp, int t)
{
    const int b = blockIdx.x, tid = threadIdx.x;
    const int wave = tid >> 6, lane = tid & 63;
    __shared__ float kr[16], ki[16];
    __shared__ float zs[768];
    __shared__ float h1s[256];
    __shared__ float h2s[128];
    __shared__ float red[8];
    if (tid < 16) { kr[tid] = keep[(size_t)b * 32 + tid * 2]; ki[tid] = keep[(size_t)b * 32 + tid * 2 + 1]; }
    __syncthreads();
    const float sd  = sd_p[0];
    const float gv  = 1.f / (1.f + expf(-gate_p[0]));
    const float bnc = 1.f / sqrtf(1.f + 1e-5f);
    float v[3]; float s = 0.f, s2 = 0.f;
#pragma unroll
    for (int j = 0; j < 3; ++j) {
        int c = tid + 256 * j;
        float den = pb_t[c];
#pragma unroll
        for (int k = 0; k < 16; ++k) {
            den = fmaf(kr[k], csC_t[k * Dv + c], den);
            den = fmaf(-ki[k], csS_t[k * Dv + c], den);
        }
        float val = z1[(size_t)b * Dv + c] + sd * den;
        v[j] = val; s += val; s2 += val * val;
    }
#pragma unroll
    for (int dd = 1; dd < 64; dd <<= 1) { s += __shfl_xor(s, dd); s2 += __shfl_xor(s2, dd); }
    if (lane == 0) { red[wave * 2] = s; red[wave * 2 + 1] = s2; }
    __syncthreads();
    const float mean = (red[0] + red[2] + red[4] + red[6]) * (1.f / 768.f);
    const float var  = (red[1] + red[3] + red[5] + red[7]) * (1.f / 768.f) - mean * mean;
    const float rstd = rsqrtf(var + 1e-5f);
#pragma unroll
    for (int j = 0; j < 3; ++j) {
        int c = tid + 256 * j;
        float z2v = (v[j] - mean) * rstd * g2[c] + b2[c];
        float z3v = gv * z2v + (1.f - gv) * z[(size_t)b * Dv + c];
        float zn  = z3v * (bng[c] * bnc) + bnb[c];
        z[(size_t)b * Dv + c] = zn;
        zs[c] = zn;
    }
    __syncthreads();
    // f1: 768 -> 256
    float h = f1b[tid];
    for (int d = 0; d < 768; ++d) h = fmaf(zs[d], f1w[(size_t)d * 256 + tid], h);
    h = h * (f1g[tid] * bnc) + f1bb[tid];
    h1s[tid] = fmaxf(h, 0.f);
    __syncthreads();
    if (tid < 128) {
        float h2 = f2b[tid];
        for (int i2 = 0; i2 < 256; ++i2) h2 = fmaf(h1s[i2], f2w[(size_t)i2 * 128 + tid], h2);
        h2 = h2 * (f2g[tid] * bnc) + f2bb[tid];
        h2s[tid] = fmaxf(h2, 0.f);
    }
    __syncthreads();
    if (tid < NCv) {
        float lg = clb[tid];
        for (int i2 = 0; i2 < 128; ++i2) lg = fmaf(h2s[i2], clw[(size_t)i2 * NCv + tid], lg);
        lg *= 0.25f;
        if (t == 0) outp[(size_t)b * NCv + tid] = lg;
        else        outp[(size_t)b * NCv + tid] += lg;
    }
}

// ---------------------------------------------------------------------------
extern "C" void kernel_launch(void* const* d_in, const int* in_sizes, int n_in,
                              void* d_out, int out_size, void* d_ws, size_t ws_size,
                              hipStream_t stream)
{
    (void)in_sizes; (void)n_in; (void)out_size; (void)ws_size;
    const float* x      = (const float*)d_in[0];
    const float* pool_w = (const float*)d_in[1];
    // d_in[2] pool_b: constant shift under softmax -> dropped
    const float* w_q   = (const float*)d_in[3];
    const float* w_k   = (const float*)d_in[4];
    const float* w_v   = (const float*)d_in[5];
    const float* b_qkv = (const float*)d_in[6];
    const float* w_o   = (const float*)d_in[7];
    const float* b_o   = (const float*)d_in[8];
    const float* ln1_g = (const float*)d_in[9];
    const float* ln1_b = (const float*)d_in[10];
    const float* ln2_g = (const float*)d_in[11];
    const float* ln2_b = (const float*)d_in[12];
    const float* s_re  = (const float*)d_in[13];
    const float* s_im  = (const float*)d_in[14];
    const float* proj_w= (const float*)d_in[15];
    const float* proj_b= (const float*)d_in[16];
    const float* bn_g  = (const float*)d_in[17];
    const float* bn_b  = (const float*)d_in[18];
    const float* gate  = (const float*)d_in[19];
    const float* s_at  = (const float*)d_in[20];
    const float* s_dn  = (const float*)d_in[21];
    const float* f1w   = (const float*)d_in[22];
    const float* f1b   = (const float*)d_in[23];
    const float* f1g   = (const float*)d_in[24];
    const float* f1bb  = (const float*)d_in[25];
    const float* f2w   = (const float*)d_in[26];
    const float* f2b   = (const float*)d_in[27];
    const float* f2g   = (const float*)d_in[28];
    const float* f2bb  = (const float*)d_in[29];
    const float* clw   = (const float*)d_in[30];
    const float* clb   = (const float*)d_in[31];
    float* out = (float*)d_out;
    float* ws  = (float*)d_ws;

    // ws layout (floats): total ~4.26M (~17 MB)
    float* twc  = ws;               // 16*768
    float* tws  = twc + 12288;      // 16*768
    float* filt = tws + 12288;      // 4*16*2
    float* csC  = filt + 128;       // 4*16*768
    float* csS  = csC + 49152;      // 4*16*768
    float* z    = csS + 49152;      // 256*768
    float* q    = z   + 196608;     // 256*768
    float* Qk   = q   + 196608;     // 256*8*768
    float* xw   = Qk  + 1572864;    // 256*8*768
    float* o    = xw  + 1572864;    // 256*768
    float* za   = o   + 196608;     // 256*768
    float* z1   = za  + 196608;     // 256*768
    float* keep = z1  + 196608;     // 256*16*2

    pre1_kernel<<<112, 256, 0, stream>>>(twc, tws, s_re, s_im, filt);
    cs_kernel<<<dim3(3, 16, 4), 256, 0, stream>>>(proj_w, twc, tws, csC, csS);

    // pooling: z[b] = softmax_s(x . pool_w) weighted sum of x
    flash_kernel<1><<<256, 512, 0, stream>>>(x, pool_w, z, 1.0f);

    const float iscale = (float)(1.0 / sqrt(96.0));
    for (int t = 0; t < 4; ++t) {
        const size_t dd = (size_t)t * Dv * Dv;
        // q = z @ w_q^T + bq
        gemm_wt<64><<<dim3(12, 4), 256, 0, stream>>>(z, Dv, w_q + dd, Dv,
                                                     b_qkv + (size_t)t * 3 * Dv, q, Dv, Dv, 0);
        // Qk[b,h,:] = W_k_h^T q_h
        gemm_wn<<<dim3(12, 4, 8), 256, 0, stream>>>(q, w_k + dd, Qk);
        // xw[b,h,:] = softmax_s(Qk.x/sqrt(DH)) weighted sum of x
        attn_flash_kernel<<<256, 512, 0, stream>>>(x, Qk, xw, iscale);
        // o = W_v xw(head) + bv
        gemm_wt<32><<<dim3(24, 4), 256, 0, stream>>>(xw, Hv * Dv, w_v + dd, Dv,
                                                     b_qkv + (size_t)t * 3 * Dv + 2 * Dv, o, Dv, Dv, 1);
        // z_attn = o @ w_o^T + b_o
        gemm_wt<64><<<dim3(12, 4), 256, 0, stream>>>(o, Dv, w_o + dd, Dv,
                                                     b_o + (size_t)t * Dv, za, Dv, Dv, 0);
        // z1 = LN(z + sa*z_attn), keep = filt * DFT16(z1)
        ln1_dft_kernel<<<256, 256, 0, stream>>>(z, za, ln1_g + (size_t)t * Dv, ln1_b + (size_t)t * Dv,
                                                s_at + t, twc, tws, filt + (size_t)t * 32, z1, keep);
        // z_den -> z2 -> z3 -> bn -> z ; out += 0.25*classify(z)
        den_cls_kernel<<<256, 256, 0, stream>>>(keep, csC + (size_t)t * 16 * Dv, csS + (size_t)t * 16 * Dv,
                                                proj_b + (size_t)t * Dv, z1, z,
                                                ln2_g + (size_t)t * Dv, ln2_b + (size_t)t * Dv,
                                                bn_g + (size_t)t * Dv, bn_b + (size_t)t * Dv,
                                                gate + t, s_dn + t,
                                                f1w, f1b, f1g, f1bb, f2w, f2b, f2g, f2bb,
                                                clw, clb, out, t);
    }
}